// Round 10
// baseline (92.274 us; speedup 1.0000x reference)
//
#include <hip/hip_runtime.h>

// QuantumDMRGLayer: B=2048, L=196, M=16, NBL=10, pos_label=98 (fixed by setup).
// Round-10 = round-9 MFMA chain + two throughput cuts:
//   1. Packed-FP32 VALU: combine + bf16 hi/lo split rewritten on 2-wide float
//      ext-vectors (-> v_pk_add/mul/fma_f32 on gfx950): ~56 scalar VALU
//      instrs/site -> ~36 (16 packed). Same fmaf arithmetic, bit-identical
//      output (absmax must stay 6.94e-18).
//   2. out_kernel merged into the chain kernel: block = 2 waves (wave 0 =
//      left chain, wave 1 = right chain, SAME 32 samples); final states meet
//      in LDS; T_out staged l-major at prologue; 320 outputs per block done
//      in-block. Saves a dispatch + the 512 KB state round-trip through the
//      0xAA-poisoned ws.
// Chain recap (verified r7-r9): site update for 32 samples = D(32x32) =
// G(32x16) x V(16x32) via v_mfma_f32_32x32x16_bf16, split-bf16 hi/lo
// (Da = Ahi*Bhi || Db = Ahi*Blo + Alo*Bhi, dep depth 2). G rows = [W0|W1]
// with bit2<->bit3 row permutation baked in at prep so each lane's D regs are
// exactly its own B-operand k-half: w[j] = x0*D[j] + x1*D[j+8], ZERO
// cross-lane ops across the whole chain. 4-site register prefetch ring.

typedef __attribute__((ext_vector_type(8))) short short8;
typedef __attribute__((ext_vector_type(16))) float floatx16;
typedef __attribute__((ext_vector_type(2))) float float2v;

#define GSITE_DW 512                 // dwords per site (hi 256 | lo 256)
#define GDIR_DW (100 * GSITE_DW)     // 100 sites per dir (2 pad)

__device__ __forceinline__ unsigned bf16_rne(unsigned u) {
    return (u + 0x7FFFu + ((u >> 16) & 1u)) >> 16;
}

// ---- prep: build split-bf16, row-permuted G streams in d_ws (as r9) ----
__global__ __launch_bounds__(256)
void prep_kernel(const float* __restrict__ AM, unsigned* __restrict__ WS)
{
    const int bid = blockIdx.x;                // 0..199
    const int dir = bid / 100;
    const int p   = bid % 100;
    const int lim = dir ? 96 : 98;
    const int a   = dir ? (193 - p) : p;
    const int t   = threadIdx.x;

    __shared__ float sM[512];                  // one site: [d][16][16]
    if (p < lim)
        ((float2*)sM)[t] = ((const float2*)(AM + a * 512))[t];
    else
        ((float2*)sM)[t] = make_float2(0.f, 0.f);   // pad sites -> zero
    __syncthreads();

    const int w    = t & 3;
    const int lane = t >> 2;
    const int kb = (lane >> 5) << 3;
    const int r  = lane & 31;
    const int rr = (r & 0x13) | ((r & 4) << 1) | ((r & 8) >> 1);  // pi(r)
    const int d = rr >> 4, nn = rr & 15;
    const int k0 = kb + 2 * w;

    float g0, g1;
    if (dir == 0) { g0 = sM[d * 256 + k0 * 16 + nn];
                    g1 = sM[d * 256 + (k0 + 1) * 16 + nn]; }
    else          { g0 = sM[d * 256 + nn * 16 + k0];
                    g1 = sM[d * 256 + nn * 16 + k0 + 1]; }

    const unsigned h0 = bf16_rne(__float_as_uint(g0));
    const unsigned h1 = bf16_rne(__float_as_uint(g1));
    const float l0f = g0 - __uint_as_float(h0 << 16);
    const float l1f = g1 - __uint_as_float(h1 << 16);
    const unsigned lo0 = bf16_rne(__float_as_uint(l0f));
    const unsigned lo1 = bf16_rne(__float_as_uint(l1f));

    unsigned* gp = WS + (dir * 100 + p) * GSITE_DW;
    gp[t]       = (h1 << 16) | h0;
    gp[256 + t] = (lo1 << 16) | lo0;
}

// ---- fused chain + epilogue: block = 32 samples, wave0=left, wave1=right ----
__global__ __launch_bounds__(128, 1)
void chain_kernel(const float* __restrict__ X,
                  const float* __restrict__ AL,
                  const float* __restrict__ AR,
                  const float* __restrict__ T,
                  const unsigned* __restrict__ WS,
                  float* __restrict__ OUT)
{
    __shared__ float sTt[2560];       // T transposed: [l][m][n]
    __shared__ float sS[2][32][16];   // final states: [dir][sample][comp]

    const int tid  = threadIdx.x;
    const int dir  = tid >> 6;                 // wave 0 = left, 1 = right
    const int lane = tid & 63;
    const int sl   = lane & 31;                // sample slot in block
    const int kb   = (lane >> 5) << 3;         // this lane's k-half base
    const int s    = (int)blockIdx.x * 32 + sl;
    const float* Xs = X + s * 392;
    const unsigned* Gb = WS + dir * GDIR_DW + lane * 4;

    // ---- prologue: stage T l-major (coalesced global read) ----
    for (int k = tid; k < 2560; k += 128) {
        const int m = k / 160, rem = k - m * 160;
        const int n = rem / 10, l = rem - n * 10;
        sTt[l * 256 + m * 16 + n] = T[k];
    }

    float2v w2[4];
    int4 vh4, vl4;
    auto packv = [&]() {                       // fp32 -> packed bf16 hi/lo
#pragma unroll
        for (int q = 0; q < 4; ++q) {
            const unsigned u0 = __float_as_uint(w2[q].x);
            const unsigned u1 = __float_as_uint(w2[q].y);
            float2v hi;
            hi.x = __uint_as_float(u0 & 0xFFFF0000u);
            hi.y = __uint_as_float(u1 & 0xFFFF0000u);
            const float2v lo = w2[q] - hi;     // v_pk_add_f32
            ((unsigned*)&vh4)[q] = __builtin_amdgcn_perm(u1, u0, 0x07060302u);
            ((unsigned*)&vl4)[q] = __builtin_amdgcn_perm(
                __float_as_uint(lo.y), __float_as_uint(lo.x), 0x07060302u);
        }
    };

    // ---- init bond vector: v[k] = x0*Ai[0][k] + x1*Ai[1][k] ----
    const float* Ai = dir ? AR : AL;
    const float2 xi = *(const float2*)(Xs + (dir ? 390 : 0));
#pragma unroll
    for (int q = 0; q < 4; ++q) {
        w2[q].x = xi.x * Ai[kb + 2 * q]     + xi.y * Ai[16 + kb + 2 * q];
        w2[q].y = xi.x * Ai[kb + 2 * q + 1] + xi.y * Ai[16 + kb + 2 * q + 1];
    }
    packv();

    // ---- 4-site register ring (G fragments + x pairs) ----
    int4 GH[4], GL[4];
    float2 xr[4];
#pragma unroll
    for (int i = 0; i < 4; ++i) {
        GH[i] = *(const int4*)(Gb + i * GSITE_DW);
        GL[i] = *(const int4*)(Gb + i * GSITE_DW + 256);
        xr[i] = *(const float2*)(Xs + (dir ? (388 - 2 * i) : (2 + 2 * i)));
    }

    auto site = [&](int j4, bool pf, int pn) {
        const short8 ah = *(short8*)&GH[j4];
        const short8 al = *(short8*)&GL[j4];
        const short8 bh = *(short8*)&vh4;
        const short8 bl = *(short8*)&vl4;
        floatx16 Da = {}, Db = {};
        Da = __builtin_amdgcn_mfma_f32_32x32x16_bf16(ah, bh, Da, 0, 0, 0);
        Db = __builtin_amdgcn_mfma_f32_32x32x16_bf16(ah, bl, Db, 0, 0, 0);
        Db = __builtin_amdgcn_mfma_f32_32x32x16_bf16(al, bh, Db, 0, 0, 0);
        const float2 xs = xr[j4];
        if (pf) {   // prefetch site pn into this ring slot (4 sites ahead)
            GH[j4] = *(const int4*)(Gb + pn * GSITE_DW);
            GL[j4] = *(const int4*)(Gb + pn * GSITE_DW + 256);
            xr[j4] = *(const float2*)(Xs + (dir ? (388 - 2 * pn)
                                                : (2 + 2 * pn)));
        }
        const float2v xx = {xs.x, xs.x}, xy = {xs.y, xs.y};
#pragma unroll
        for (int q = 0; q < 4; ++q) {          // D[j]=W0, D[j+8]=W1, k=kb+j
            const float2v da = {Da[2 * q],     Da[2 * q + 1]};
            const float2v db = {Db[2 * q],     Db[2 * q + 1]};
            const float2v ea = {Da[2 * q + 8], Da[2 * q + 9]};
            const float2v eb = {Db[2 * q + 8], Db[2 * q + 9]};
            const float2v s0 = da + db;        // v_pk_add_f32
            const float2v s1 = ea + eb;
            w2[q] = __builtin_elementwise_fma(xx, s0, xy * s1);  // pk_fma
        }
        packv();
    };

    // ---- 24 chunks x 4 sites = 96 sites, branch-free ----
    for (int c = 0; c < 24; ++c) {
#pragma unroll
        for (int j4 = 0; j4 < 4; ++j4)
            site(j4, true, 4 * c + j4 + 4);    // pn <= 99, pad sites exist
    }
    // left chain has 2 extra sites (96, 97) already in ring slots 0, 1
    if (dir == 0) {
        site(0, false, 0);
        site(1, false, 0);
    }

    // ---- states meet in LDS ----
#pragma unroll
    for (int q = 0; q < 4; ++q)
        *(float2*)&sS[dir][sl][kb + 2 * q] = make_float2(w2[q].x, w2[q].y);
    __syncthreads();

    // ---- epilogue: out[s,l] = sum_{m,n} L[m] Tt[l][m][n] R[n] ----
    for (int o = tid; o < 320; o += 128) {
        const int sm = o / 10, l = o - sm * 10;
        const float* L = sS[0][sm];
        const float* R = sS[1][sm];
        const float4 Ra = *(const float4*)(R);
        const float4 Rb = *(const float4*)(R + 4);
        const float4 Rc = *(const float4*)(R + 8);
        const float4 Rd = *(const float4*)(R + 12);
        const float* Tp = sTt + l * 256;
        float acc = 0.f;
#pragma unroll
        for (int m = 0; m < 16; ++m) {
            const float lm = L[m];
            const float4 t0 = *(const float4*)(Tp + m * 16);
            const float4 t1 = *(const float4*)(Tp + m * 16 + 4);
            const float4 t2 = *(const float4*)(Tp + m * 16 + 8);
            const float4 t3 = *(const float4*)(Tp + m * 16 + 12);
            acc = fmaf(lm * Ra.x, t0.x, acc);
            acc = fmaf(lm * Ra.y, t0.y, acc);
            acc = fmaf(lm * Ra.z, t0.z, acc);
            acc = fmaf(lm * Ra.w, t0.w, acc);
            acc = fmaf(lm * Rb.x, t1.x, acc);
            acc = fmaf(lm * Rb.y, t1.y, acc);
            acc = fmaf(lm * Rb.z, t1.z, acc);
            acc = fmaf(lm * Rb.w, t1.w, acc);
            acc = fmaf(lm * Rc.x, t2.x, acc);
            acc = fmaf(lm * Rc.y, t2.y, acc);
            acc = fmaf(lm * Rc.z, t2.z, acc);
            acc = fmaf(lm * Rc.w, t2.w, acc);
            acc = fmaf(lm * Rd.x, t3.x, acc);
            acc = fmaf(lm * Rd.y, t3.y, acc);
            acc = fmaf(lm * Rd.z, t3.z, acc);
            acc = fmaf(lm * Rd.w, t3.w, acc);
        }
        OUT[((int)blockIdx.x * 32 + sm) * 10 + l] = acc;
    }
}

extern "C" void kernel_launch(void* const* d_in, const int* in_sizes, int n_in,
                              void* d_out, int out_size, void* d_ws, size_t ws_size,
                              hipStream_t stream)
{
    const float* X  = (const float*)d_in[0];   // (2048,196,2)
    const float* AL = (const float*)d_in[1];   // (2,16)
    const float* AM = (const float*)d_in[2];   // (194,2,16,16)
    const float* AR = (const float*)d_in[3];   // (2,16)
    const float* T  = (const float*)d_in[4];   // (16,16,10)
    (void)in_sizes; (void)n_in; (void)out_size; (void)ws_size;
    unsigned* WS = (unsigned*)d_ws;            // G streams: 400 KB
    float* OUT   = (float*)d_out;              // (2048,10)

    hipLaunchKernelGGL(prep_kernel,  dim3(200), dim3(256), 0, stream, AM, WS);
    hipLaunchKernelGGL(chain_kernel, dim3(64),  dim3(128), 0, stream,
                       X, AL, AR, T, WS, OUT);
}